// Round 7
// baseline (5314.841 us; speedup 1.0000x reference)
//
#include <hip/hip_runtime.h>
#include <hip/hip_bf16.h>

#define SEQ   512
#define HID   1024
#define NBLK  256
#define NTHR  256
#define PADK  2056   // LDS weight row stride (shorts); 4112 B, 16B-aligned
#define GPS   36     // gparts row stride (dwords) — breaks stride-32 conflicts

typedef __attribute__((ext_vector_type(8))) short bf16x8;
typedef __attribute__((ext_vector_type(4))) float f32x4;
typedef __attribute__((ext_vector_type(2))) float f32x2;

struct Params {
  const float* x;        // [64][512][1024] f32
  const float* Wi[4];    // [1024][1024] f32, gates i,f,g,o
  const float* Wh[4];
  const float* bi[4];
  const float* bh[4];
  float* out;            // f32 [h_T | c_T]; fallback tier also uses halves as h ping-pong
  const short* xbf;      // mode 1: x pre-converted to bf16
  short* hb0;            // mode 1: bf16 h ping-pong (sc1/IF-coherent)
  short* hb1;
  unsigned* arrive;      // mode 1: 4 step-counters at [c*32] (128 B apart)
                         // mode 0: padded flag slots arrive[bid*32]
  unsigned* gen;         // generation flag (fallback tier only)
};

__device__ __forceinline__ float sig_(float v)  { return 1.0f / (1.0f + __expf(-v)); }
__device__ __forceinline__ float tanh_(float v) { return 1.0f - 2.0f / (__expf(2.0f * v) + 1.0f); }

__device__ __forceinline__ short f2b(float f) {   // f32 -> bf16 RNE
  unsigned u = __builtin_bit_cast(unsigned, f);
  u += 0x7FFFu + ((u >> 16) & 1u);
  return (short)(u >> 16);
}
__device__ __forceinline__ bf16x8 cvt8(const float* p) {
  f32x4 a = *(const f32x4*)p;
  f32x4 b = *(const f32x4*)(p + 4);
  bf16x8 r;
  r[0] = f2b(a[0]); r[1] = f2b(a[1]); r[2] = f2b(a[2]); r[3] = f2b(a[3]);
  r[4] = f2b(b[0]); r[5] = f2b(b[1]); r[6] = f2b(b[2]); r[7] = f2b(b[3]);
  return r;
}

// 16B load bypassing L1/L2 (device-coherent, served by Infinity Cache).
// Caller MUST batch these then execute wait_vm0() + launder before use.
__device__ __forceinline__ bf16x8 ld16_sc1(const short* p) {
  bf16x8 r;
  asm volatile("global_load_dwordx4 %0, %1, off sc1" : "=v"(r) : "v"(p));
  return r;
}
__device__ __forceinline__ void wait_vm0() {
  asm volatile("s_waitcnt vmcnt(0)" ::: "memory");
}

__global__ __launch_bounds__(256) void init_ws(unsigned* bar, unsigned* hzero, int hn) {
  int i = blockIdx.x * blockDim.x + threadIdx.x;
  if (i < 8448) bar[i] = 0u;              // counter/flag region + gen + pad
  if (i < hn) hzero[i] = 0u;              // zero h(t=0) buffer
}

__global__ __launch_bounds__(256) void cvt_x(const float* __restrict__ x,
                                             short* __restrict__ xb) {
  size_t i = ((size_t)blockIdx.x * 256 + threadIdx.x) * 8;
  *(bf16x8*)(xb + i) = cvt8(x + i);
}

// ---- fallback-tier barrier (fence-based; correctness only) ----
__device__ __forceinline__ void gbar_fence(unsigned* arrive, unsigned* gen,
                                           int tid, int bid, unsigned tgt) {
  __syncthreads();
  if (bid == 0) {
    if (tid != 0) {
      int polls = 0;
      while (__hip_atomic_load(&arrive[tid * 32], __ATOMIC_RELAXED,
                               __HIP_MEMORY_SCOPE_AGENT) < tgt) {
        __builtin_amdgcn_s_sleep(1);
        if (++polls > (1 << 22)) break;
      }
    }
    __syncthreads();
    if (tid == 0) {
      __threadfence();
      __hip_atomic_store(gen, tgt, __ATOMIC_RELEASE, __HIP_MEMORY_SCOPE_AGENT);
    }
    __syncthreads();
  } else {
    if (tid == 0) {
      __threadfence();
      __hip_atomic_store(&arrive[bid * 32], tgt, __ATOMIC_RELEASE,
                         __HIP_MEMORY_SCOPE_AGENT);
      int polls = 0;
      while (__hip_atomic_load(gen, __ATOMIC_RELAXED,
                               __HIP_MEMORY_SCOPE_AGENT) < tgt) {
        __builtin_amdgcn_s_sleep(1);
        if (++polls > (1 << 22)) break;
      }
      __threadfence();
    }
    __syncthreads();
  }
}

// MODE: 1 = xbf + sc1 ping-pong h + ATOMIC-COUNTER signaling; 0 = f32 fallback
// LDS: bls[32][PADK] bf16 (row = interleaved gate-col 4*jl+g), 131584 B
//      gparts[4][32][GPS] f32, cst[32][8] f32, bias_s[32] f32    = 151168 B
template <int MODE>
__global__ __launch_bounds__(NTHR, 1) void lstm_persistent(Params p) {
  extern __shared__ char smem[];
  short* bls    = (short*)smem;
  float* gparts = (float*)(smem + 131584);
  float* cst    = (float*)(smem + 131584 + 18432);
  float* bias_s = (float*)(smem + 131584 + 18432 + 1024);

  const int tid = threadIdx.x;
  const int bid = blockIdx.x;
  const int cg  = bid & 127;       // gate-col group: cols [32cg, 32cg+32)
  const int mh  = bid >> 7;        // batch half
  const int r0  = mh * 32;
  const int j0  = cg * 8;          // hidden cols [j0, j0+8)

  // ---- one-time: stage bf16 weight slab, interleaved col = 4*jl + g ----
  {
    const int g    = tid & 3;
    const int krow = tid >> 2;     // 0..63
    const float* wi = p.Wi[g];
    const float* wh = p.Wh[g];
    for (int kb = 0; kb < 2048; kb += 64) {
      int k = kb + krow;
      const float* src = (k < HID) ? (wi + (size_t)k * HID + j0)
                                   : (wh + (size_t)(k - HID) * HID + j0);
      f32x4 va = *(const f32x4*)src;
      f32x4 vb = *(const f32x4*)(src + 4);
      #pragma unroll
      for (int jj = 0; jj < 4; ++jj) {
        bls[(4 * jj + g) * PADK + k]       = f2b(va[jj]);
        bls[(4 * (jj + 4) + g) * PADK + k] = f2b(vb[jj]);
      }
    }
  }
  if (tid < 32) {
    int g = tid & 3, j = j0 + (tid >> 2);
    bias_s[tid] = p.bi[g][j] + p.bh[g][j];
  }
  if (tid < 128) { cst[2 * tid] = 0.0f; cst[2 * tid + 1] = 0.0f; }
  __syncthreads();

  const int lane = tid & 63;
  const int ksl  = tid >> 6;       // K-slice 0..3; 0,1 = x-part, 2,3 = h-part
  const int m16  = lane & 15;
  const int quad = lane >> 4;
  const size_t rm0 = (size_t)(r0 + m16);
  const size_t rm1 = (size_t)(r0 + 16 + m16);
  const short* bB0 = bls + (size_t)m16 * PADK + ksl * 512 + quad * 8;        // nt=0
  const short* bB1 = bls + (size_t)(16 + m16) * PADK + ksl * 512 + quad * 8; // nt=1

  // Counter signaling (mode 1): one counter per (mh, K-half), 128 B apart.
  //  - consumers: ALL 64 lanes poll the SAME address -> 1 IF txn per wave per
  //    poll round (vs 64 padded-flag lines) — kills the poll storm.
  //  - producers: 2 fire-and-forget atomic adds per block per step (one per
  //    cell wave, after that wave's own vmcnt drain) — no line ping-pong.
  // Consumer (mh,ksl) waits counter >= 128*t (64 producer blocks x 2 waves).
  unsigned* mycnt =
      p.arrive + (size_t)(mh * 2 + ((ksl - 2) & 1)) * 32;   // h-waves' counter
  unsigned* prodcnt =
      p.arrive + (size_t)(mh * 2 + (cg >> 6)) * 32;         // this block's counter

  float cfin0 = 0.0f, cfin1 = 0.0f;

  for (int t = 0; t < SEQ; ++t) {
    f32x4 acc00 = {0,0,0,0}, acc01 = {0,0,0,0};
    f32x4 acc10 = {0,0,0,0}, acc11 = {0,0,0,0};

    if constexpr (MODE == 1) {
      if (ksl < 2) {
        // x-part: bf16 pre-converted, runs ahead, never waits on counters
        const short* xb = p.xbf + ksl * 512 + quad * 8 + (size_t)t * HID;
        const short* pa0 = xb + rm0 * (SEQ * HID);
        const short* pa1 = xb + rm1 * (SEQ * HID);
        #pragma unroll 4
        for (int ki = 0; ki < 16; ++ki) {
          bf16x8 a0 = *(const bf16x8*)(pa0 + ki * 32);
          bf16x8 a1 = *(const bf16x8*)(pa1 + ki * 32);
          bf16x8 b0 = *(const bf16x8*)(bB0 + ki * 32);
          bf16x8 b1 = *(const bf16x8*)(bB1 + ki * 32);
          acc00 = __builtin_amdgcn_mfma_f32_16x16x32_bf16(a0, b0, acc00, 0, 0, 0);
          acc01 = __builtin_amdgcn_mfma_f32_16x16x32_bf16(a0, b1, acc01, 0, 0, 0);
          acc10 = __builtin_amdgcn_mfma_f32_16x16x32_bf16(a1, b0, acc10, 0, 0, 0);
          acc11 = __builtin_amdgcn_mfma_f32_16x16x32_bf16(a1, b1, acc11, 0, 0, 0);
        }
      } else if (t > 0) {          // t==0: h=0, h-MFMA contributes 0 — skip
        // single-line wave poll: one coalesced IF read per round
        {
          const unsigned tgt = 128u * (unsigned)t;
          int polls = 0;
          while (__hip_atomic_load(mycnt, __ATOMIC_RELAXED,
                                   __HIP_MEMORY_SCOPE_AGENT) < tgt) {
            __builtin_amdgcn_s_sleep(1);
            if (++polls > (1 << 22)) break;
          }
        }
        // batched IF-coherent sc1 loads, single vmcnt wait (round-3 mechanism)
        const short* hr = ((t & 1) ? p.hb1 : p.hb0) + (ksl - 2) * 512 + quad * 8;
        const short* pa0 = hr + rm0 * HID;
        const short* pa1 = hr + rm1 * HID;
        bf16x8 A0[16], A1[16];
        #pragma unroll
        for (int ki = 0; ki < 16; ++ki) {
          A0[ki] = ld16_sc1(pa0 + ki * 32);
          A1[ki] = ld16_sc1(pa1 + ki * 32);
        }
        wait_vm0();
        #pragma unroll
        for (int ki = 0; ki < 16; ++ki) {   // launder: pin MFMAs after the wait
          asm volatile("" : "+v"(A0[ki]));
          asm volatile("" : "+v"(A1[ki]));
        }
        #pragma unroll
        for (int ki = 0; ki < 16; ++ki) {
          bf16x8 b0 = *(const bf16x8*)(bB0 + ki * 32);
          bf16x8 b1 = *(const bf16x8*)(bB1 + ki * 32);
          acc00 = __builtin_amdgcn_mfma_f32_16x16x32_bf16(A0[ki], b0, acc00, 0, 0, 0);
          acc01 = __builtin_amdgcn_mfma_f32_16x16x32_bf16(A0[ki], b1, acc01, 0, 0, 0);
          acc10 = __builtin_amdgcn_mfma_f32_16x16x32_bf16(A1[ki], b0, acc10, 0, 0, 0);
          acc11 = __builtin_amdgcn_mfma_f32_16x16x32_bf16(A1[ki], b1, acc11, 0, 0, 0);
        }
      }
    } else {
      const float *fa0, *fa1;
      if (ksl < 2) {
        const float* xb = p.x + ksl * 512 + quad * 8 + (size_t)t * HID;
        fa0 = xb + rm0 * (SEQ * HID);
        fa1 = xb + rm1 * (SEQ * HID);
      } else {
        const float* hr = (p.out + ((t & 1) ? 65536 : 0)) + (ksl - 2) * 512 + quad * 8;
        fa0 = hr + rm0 * HID;
        fa1 = hr + rm1 * HID;
      }
      #pragma unroll 2
      for (int ki = 0; ki < 16; ++ki) {
        bf16x8 a0 = cvt8(fa0 + ki * 32);
        bf16x8 a1 = cvt8(fa1 + ki * 32);
        bf16x8 b0 = *(const bf16x8*)(bB0 + ki * 32);
        bf16x8 b1 = *(const bf16x8*)(bB1 + ki * 32);
        acc00 = __builtin_amdgcn_mfma_f32_16x16x32_bf16(a0, b0, acc00, 0, 0, 0);
        acc01 = __builtin_amdgcn_mfma_f32_16x16x32_bf16(a0, b1, acc01, 0, 0, 0);
        acc10 = __builtin_amdgcn_mfma_f32_16x16x32_bf16(a1, b0, acc10, 0, 0, 0);
        acc11 = __builtin_amdgcn_mfma_f32_16x16x32_bf16(a1, b1, acc11, 0, 0, 0);
      }
    }

    // C layout: col = lane&15, row = quad*4 + reg (HW-verified)
    {
      float* gp = gparts + ksl * (32 * GPS);
      #pragma unroll
      for (int r = 0; r < 4; ++r) {
        gp[(quad * 4 + r) * GPS + m16]           = acc00[r];
        gp[(quad * 4 + r) * GPS + 16 + m16]      = acc01[r];
        gp[(16 + quad * 4 + r) * GPS + m16]      = acc10[r];
        gp[(16 + quad * 4 + r) * GPS + 16 + m16] = acc11[r];
      }
    }
    __syncthreads();   // S2: gparts(t) complete before cell reads

    // ---- cell update: 32 rows x 4 col-pairs (128 threads) ----
    if (tid < 128) {
      int rl = tid >> 2, jp = tid & 3;
      f32x4 ga = {0,0,0,0}, gb = {0,0,0,0};
      #pragma unroll
      for (int s = 0; s < 4; ++s) {
        const float* gp = gparts + s * (32 * GPS) + rl * GPS + jp * 8;
        ga += *(const f32x4*)gp;
        gb += *(const f32x4*)(gp + 4);
      }
      f32x4 ba = *(const f32x4*)(bias_s + jp * 8);
      f32x4 bb = *(const f32x4*)(bias_s + jp * 8 + 4);

      float i0 = sig_(ga[0] + ba[0]);
      float f0 = sig_(ga[1] + ba[1]);
      float g0 = tanh_(ga[2] + ba[2]);
      float o0 = sig_(ga[3] + ba[3]);
      float i1 = sig_(gb[0] + bb[0]);
      float f1 = sig_(gb[1] + bb[1]);
      float g1 = tanh_(gb[2] + bb[2]);
      float o1 = sig_(gb[3] + bb[3]);

      int ci = rl * 8 + jp * 2;
      float c0 = f0 * cst[ci]     + i0 * g0;
      float c1 = f1 * cst[ci + 1] + i1 * g1;
      cst[ci] = c0; cst[ci + 1] = c1;
      float h0v = o0 * tanh_(c0);
      float h1v = o1 * tanh_(c1);

      size_t off = (size_t)(r0 + rl) * HID + j0 + jp * 2;
      if constexpr (MODE == 1) {
        if (t < SEQ - 1) {
          short* hw = (t & 1) ? p.hb0 : p.hb1;
          unsigned u = (unsigned)(unsigned short)f2b(h0v) |
                       ((unsigned)(unsigned short)f2b(h1v) << 16);
          // IF-coherent h store (sc1, write-through)
          __hip_atomic_store((unsigned*)(hw + off), u, __ATOMIC_RELAXED,
                             __HIP_MEMORY_SCOPE_AGENT);
          // per-wave early signal: this wave's h stores acked at IF, then one
          // fire-and-forget atomic add (lanes 0 and 64) — consumers can start
          // without waiting for this block's S3.
          wait_vm0();
          if ((tid & 63) == 0)
            (void)__hip_atomic_fetch_add(prodcnt, 1u, __ATOMIC_RELAXED,
                                         __HIP_MEMORY_SCOPE_AGENT);
        } else {
          f32x2 hv = {h0v, h1v}; *(f32x2*)(p.out + off) = hv;
          f32x2 cv = {c0, c1};   *(f32x2*)(p.out + 65536 + off) = cv;
        }
      } else {
        float* hw = p.out + ((t & 1) ? 0 : 65536);
        f32x2 hv = {h0v, h1v};
        *(f32x2*)(hw + off) = hv;
        if (t == SEQ - 1) { cfin0 = c0; cfin1 = c1; }
      }
    }

    if constexpr (MODE == 1) {
      // S3: LDS safety only (h-waves of t+1 must not overwrite gparts slices
      // while cell(t) could still be reading) — off the signal critical path.
      __syncthreads();
    } else {
      if (t < SEQ - 1)
        gbar_fence(p.arrive, p.gen, tid, bid, (unsigned)(t + 1));
    }
  }

  if constexpr (MODE == 0) {
    if (tid < 128) {
      int rl = tid >> 2, jp = tid & 3;
      size_t off = (size_t)(r0 + rl) * HID + j0 + jp * 2;
      f32x2 cv = {cfin0, cfin1};
      *(f32x2*)(p.out + 65536 + off) = cv;
    }
  }
}

extern "C" void kernel_launch(void* const* d_in, const int* in_sizes, int n_in,
                              void* d_out, int out_size, void* d_ws, size_t ws_size,
                              hipStream_t stream) {
  Params prm;
  prm.x = (const float*)d_in[0];
  for (int g = 0; g < 4; ++g) {
    prm.Wi[g] = (const float*)d_in[1 + g];
    prm.Wh[g] = (const float*)d_in[5 + g];
    prm.bi[g] = (const float*)d_in[9 + 2 * g];
    prm.bh[g] = (const float*)d_in[10 + 2 * g];
  }
  prm.out    = (float*)d_out;
  prm.arrive = (unsigned*)d_ws;
  prm.gen    = prm.arrive + 8192;          // own line after counter/flag region
  prm.xbf = nullptr; prm.hb0 = nullptr; prm.hb1 = nullptr;

  const size_t XBF   = 67108864;                      // 64 MiB
  const size_t need1 = 65536 + XBF + 2 * 131072;      // 67,436,544 (known avail.)
  const int mode = (ws_size >= need1) ? 1 : 0;

  if (mode == 1) {
    prm.xbf = (const short*)((char*)d_ws + 65536);
    prm.hb0 = (short*)((char*)d_ws + 65536 + XBF);
    prm.hb1 = prm.hb0 + 65536;
  }

  const int smem_bytes = 131584 + 18432 + 1024 + 128;   // 151168
  hipFuncSetAttribute((const void*)lstm_persistent<1>,
                      hipFuncAttributeMaxDynamicSharedMemorySize, smem_bytes);
  hipFuncSetAttribute((const void*)lstm_persistent<0>,
                      hipFuncAttributeMaxDynamicSharedMemorySize, smem_bytes);

  if (mode == 1) {
    init_ws<<<256, 256, 0, stream>>>((unsigned*)d_ws, (unsigned*)prm.hb0, 32768);
    cvt_x<<<16384, 256, 0, stream>>>(prm.x, (short*)prm.xbf);
    lstm_persistent<1><<<NBLK, NTHR, smem_bytes, stream>>>(prm);
  } else {
    init_ws<<<256, 256, 0, stream>>>((unsigned*)d_ws, (unsigned*)d_out, 65536);
    lstm_persistent<0><<<NBLK, NTHR, smem_bytes, stream>>>(prm);
  }
}

// Round 8
// 3471.370 us; speedup vs baseline: 1.5310x; 1.5310x over previous
//
#include <hip/hip_runtime.h>
#include <hip/hip_bf16.h>

#define SEQ   512
#define HID   1024
#define NBLK  256
#define NTHR  256
#define PADK  2056   // LDS weight row stride (shorts); 4112 B, 16B-aligned
#define GPS   36     // gparts row stride (dwords) — breaks stride-32 conflicts

typedef __attribute__((ext_vector_type(8))) short bf16x8;
typedef __attribute__((ext_vector_type(4))) float f32x4;
typedef __attribute__((ext_vector_type(2))) float f32x2;

struct Params {
  const float* x;        // [64][512][1024] f32
  const float* Wi[4];    // [1024][1024] f32, gates i,f,g,o
  const float* Wh[4];
  const float* bi[4];
  const float* bh[4];
  float* out;            // f32 [h_T | c_T]; fallback tier also uses halves as h ping-pong
  const short* xbf;      // mode 1: x pre-converted to bf16
  short* hb0;            // mode 1: bf16 h ping-pong (sc1/IF-coherent)
  short* hb1;
  unsigned* arrive;      // PADDED flags arrive[lb*32] (128 B per producer line)
  unsigned* gen;         // generation flag (fallback tier only)
};

__device__ __forceinline__ float sig_(float v)  { return 1.0f / (1.0f + __expf(-v)); }
__device__ __forceinline__ float tanh_(float v) { return 1.0f - 2.0f / (__expf(2.0f * v) + 1.0f); }

__device__ __forceinline__ short f2b(float f) {   // f32 -> bf16 RNE
  unsigned u = __builtin_bit_cast(unsigned, f);
  u += 0x7FFFu + ((u >> 16) & 1u);
  return (short)(u >> 16);
}
__device__ __forceinline__ bf16x8 cvt8(const float* p) {
  f32x4 a = *(const f32x4*)p;
  f32x4 b = *(const f32x4*)(p + 4);
  bf16x8 r;
  r[0] = f2b(a[0]); r[1] = f2b(a[1]); r[2] = f2b(a[2]); r[3] = f2b(a[3]);
  r[4] = f2b(b[0]); r[5] = f2b(b[1]); r[6] = f2b(b[2]); r[7] = f2b(b[3]);
  return r;
}

// 16B load bypassing L1/L2 (device-coherent, served by Infinity Cache).
// Caller MUST batch these then execute wait_vm0() + launder before use.
__device__ __forceinline__ bf16x8 ld16_sc1(const short* p) {
  bf16x8 r;
  asm volatile("global_load_dwordx4 %0, %1, off sc1" : "=v"(r) : "v"(p));
  return r;
}
__device__ __forceinline__ void wait_vm0() {
  asm volatile("s_waitcnt vmcnt(0)" ::: "memory");
}

__global__ __launch_bounds__(256) void init_ws(unsigned* bar, unsigned* hzero, int hn) {
  int i = blockIdx.x * blockDim.x + threadIdx.x;
  if (i < 8448) bar[i] = 0u;              // flag slots (8192) + gen + pad
  if (i < hn) hzero[i] = 0u;              // zero h(t=0) buffer
}

__global__ __launch_bounds__(256) void cvt_x(const float* __restrict__ x,
                                             short* __restrict__ xb) {
  size_t i = ((size_t)blockIdx.x * 256 + threadIdx.x) * 8;
  *(bf16x8*)(xb + i) = cvt8(x + i);
}

// ---- fallback-tier barrier (fence-based; correctness only) ----
__device__ __forceinline__ void gbar_fence(unsigned* arrive, unsigned* gen,
                                           int tid, int bid, unsigned tgt) {
  __syncthreads();
  if (bid == 0) {
    if (tid != 0) {
      int polls = 0;
      while (__hip_atomic_load(&arrive[tid * 32], __ATOMIC_RELAXED,
                               __HIP_MEMORY_SCOPE_AGENT) < tgt) {
        __builtin_amdgcn_s_sleep(1);
        if (++polls > (1 << 22)) break;
      }
    }
    __syncthreads();
    if (tid == 0) {
      __threadfence();
      __hip_atomic_store(gen, tgt, __ATOMIC_RELEASE, __HIP_MEMORY_SCOPE_AGENT);
    }
    __syncthreads();
  } else {
    if (tid == 0) {
      __threadfence();
      __hip_atomic_store(&arrive[bid * 32], tgt, __ATOMIC_RELEASE,
                         __HIP_MEMORY_SCOPE_AGENT);
      int polls = 0;
      while (__hip_atomic_load(gen, __ATOMIC_RELAXED,
                               __HIP_MEMORY_SCOPE_AGENT) < tgt) {
        __builtin_amdgcn_s_sleep(1);
        if (++polls > (1 << 22)) break;
      }
      __threadfence();
    }
    __syncthreads();
  }
}

// MODE: 1 = xbf + sc1 ping-pong h + one-hop padded flags + ANTI-THROTTLE poll
//       (busy FMA-chain pacing instead of s_sleep: keeps SIMDs issuing so the
//        DVFS governor holds high clocks — R3/R0 counters imply ~740 MHz when
//        waves sleep: MfmaUtil 6.3% x step = 5060 cy vs 6.87 us wall);
//       0 = f32 fallback
// LDS: bls[32][PADK] bf16 (row = interleaved gate-col 4*jl+g), 131584 B
//      gparts[4][32][GPS] f32, cst[32][8] f32, bias_s[32] f32    = 151168 B
template <int MODE>
__global__ __launch_bounds__(NTHR, 1) void lstm_persistent(Params p) {
  extern __shared__ char smem[];
  short* bls    = (short*)smem;
  float* gparts = (float*)(smem + 131584);
  float* cst    = (float*)(smem + 131584 + 18432);
  float* bias_s = (float*)(smem + 131584 + 18432 + 1024);

  const int tid = threadIdx.x;
  const int bid = blockIdx.x;
  const int cg  = bid & 127;       // gate-col group: cols [32cg, 32cg+32)
  const int mh  = bid >> 7;        // batch half
  const int r0  = mh * 32;
  const int j0  = cg * 8;          // hidden cols [j0, j0+8)

  // ---- one-time: stage bf16 weight slab, interleaved col = 4*jl + g ----
  {
    const int g    = tid & 3;
    const int krow = tid >> 2;     // 0..63
    const float* wi = p.Wi[g];
    const float* wh = p.Wh[g];
    for (int kb = 0; kb < 2048; kb += 64) {
      int k = kb + krow;
      const float* src = (k < HID) ? (wi + (size_t)k * HID + j0)
                                   : (wh + (size_t)(k - HID) * HID + j0);
      f32x4 va = *(const f32x4*)src;
      f32x4 vb = *(const f32x4*)(src + 4);
      #pragma unroll
      for (int jj = 0; jj < 4; ++jj) {
        bls[(4 * jj + g) * PADK + k]       = f2b(va[jj]);
        bls[(4 * (jj + 4) + g) * PADK + k] = f2b(vb[jj]);
      }
    }
  }
  if (tid < 32) {
    int g = tid & 3, j = j0 + (tid >> 2);
    bias_s[tid] = p.bi[g][j] + p.bh[g][j];
  }
  if (tid < 128) { cst[2 * tid] = 0.0f; cst[2 * tid + 1] = 0.0f; }
  __syncthreads();

  const int lane = tid & 63;
  const int ksl  = tid >> 6;       // K-slice 0..3; 0,1 = x-part, 2,3 = h-part
  const int m16  = lane & 15;
  const int quad = lane >> 4;
  const size_t rm0 = (size_t)(r0 + m16);
  const size_t rm1 = (size_t)(r0 + 16 + m16);
  const short* bB0 = bls + (size_t)m16 * PADK + ksl * 512 + quad * 8;        // nt=0
  const short* bB1 = bls + (size_t)(16 + m16) * PADK + ksl * 512 + quad * 8; // nt=1

  // Each h-wave depends on exactly the 64 producer blocks of its K-half:
  // ksl=2 reads h cols [0,512) <- blocks mh*128+[0,64); ksl=3 <- +64.
  // Lane L polls producer (mh*128 + (ksl-2)*64 + L); divergent loop = wave AND.
  // PADDED flag lines (128 B/producer): R5/R7 showed concentrating flag
  // traffic on few lines (packed dwords / single atomic counter) serializes
  // at the IF bank and regresses — keep the spread layout.
  const unsigned* myflag =
      p.arrive + (size_t)(mh * 128 + (ksl - 2) * 64 + lane) * 32;

  float cfin0 = 0.0f, cfin1 = 0.0f;

  for (int t = 0; t < SEQ; ++t) {
    f32x4 acc00 = {0,0,0,0}, acc01 = {0,0,0,0};
    f32x4 acc10 = {0,0,0,0}, acc11 = {0,0,0,0};

    if constexpr (MODE == 1) {
      if (ksl < 2) {
        // x-part: bf16 pre-converted, runs ahead, never waits on flags
        const short* xb = p.xbf + ksl * 512 + quad * 8 + (size_t)t * HID;
        const short* pa0 = xb + rm0 * (SEQ * HID);
        const short* pa1 = xb + rm1 * (SEQ * HID);
        #pragma unroll 4
        for (int ki = 0; ki < 16; ++ki) {
          bf16x8 a0 = *(const bf16x8*)(pa0 + ki * 32);
          bf16x8 a1 = *(const bf16x8*)(pa1 + ki * 32);
          bf16x8 b0 = *(const bf16x8*)(bB0 + ki * 32);
          bf16x8 b1 = *(const bf16x8*)(bB1 + ki * 32);
          acc00 = __builtin_amdgcn_mfma_f32_16x16x32_bf16(a0, b0, acc00, 0, 0, 0);
          acc01 = __builtin_amdgcn_mfma_f32_16x16x32_bf16(a0, b1, acc01, 0, 0, 0);
          acc10 = __builtin_amdgcn_mfma_f32_16x16x32_bf16(a1, b0, acc10, 0, 0, 0);
          acc11 = __builtin_amdgcn_mfma_f32_16x16x32_bf16(a1, b1, acc11, 0, 0, 0);
        }
      } else if (t > 0) {          // t==0: h=0, h-MFMA contributes 0 — skip
        // one-hop flag wait, ANTI-THROTTLE pacing: dependent-FMA delay chain
        // (~256 cy) between polls instead of s_sleep — same poll rate, but the
        // SIMD keeps issuing so DVFS holds boost clocks.
        if (__hip_atomic_load(myflag, __ATOMIC_RELAXED,
                              __HIP_MEMORY_SCOPE_AGENT) < (unsigned)t) {
          float z = (float)(lane + 1);
          int polls = 0;
          do {
            #pragma unroll 1
            for (int d = 0; d < 64; ++d)      // 64 dependent v_fma: ~256 cy busy
              z = __builtin_fmaf(z, 1.0000001f, 1.1920929e-7f);
            asm volatile("" : "+v"(z));       // keep chain live each round
            if (++polls > (1 << 20)) break;
          } while (__hip_atomic_load(myflag, __ATOMIC_RELAXED,
                                     __HIP_MEMORY_SCOPE_AGENT) < (unsigned)t);
        }
        // batched IF-coherent sc1 loads, single vmcnt wait (round-3 mechanism)
        const short* hr = ((t & 1) ? p.hb1 : p.hb0) + (ksl - 2) * 512 + quad * 8;
        const short* pa0 = hr + rm0 * HID;
        const short* pa1 = hr + rm1 * HID;
        bf16x8 A0[16], A1[16];
        #pragma unroll
        for (int ki = 0; ki < 16; ++ki) {
          A0[ki] = ld16_sc1(pa0 + ki * 32);
          A1[ki] = ld16_sc1(pa1 + ki * 32);
        }
        wait_vm0();
        #pragma unroll
        for (int ki = 0; ki < 16; ++ki) {   // launder: pin MFMAs after the wait
          asm volatile("" : "+v"(A0[ki]));
          asm volatile("" : "+v"(A1[ki]));
        }
        #pragma unroll
        for (int ki = 0; ki < 16; ++ki) {
          bf16x8 b0 = *(const bf16x8*)(bB0 + ki * 32);
          bf16x8 b1 = *(const bf16x8*)(bB1 + ki * 32);
          acc00 = __builtin_amdgcn_mfma_f32_16x16x32_bf16(A0[ki], b0, acc00, 0, 0, 0);
          acc01 = __builtin_amdgcn_mfma_f32_16x16x32_bf16(A0[ki], b1, acc01, 0, 0, 0);
          acc10 = __builtin_amdgcn_mfma_f32_16x16x32_bf16(A1[ki], b0, acc10, 0, 0, 0);
          acc11 = __builtin_amdgcn_mfma_f32_16x16x32_bf16(A1[ki], b1, acc11, 0, 0, 0);
        }
      }
    } else {
      const float *fa0, *fa1;
      if (ksl < 2) {
        const float* xb = p.x + ksl * 512 + quad * 8 + (size_t)t * HID;
        fa0 = xb + rm0 * (SEQ * HID);
        fa1 = xb + rm1 * (SEQ * HID);
      } else {
        const float* hr = (p.out + ((t & 1) ? 65536 : 0)) + (ksl - 2) * 512 + quad * 8;
        fa0 = hr + rm0 * HID;
        fa1 = hr + rm1 * HID;
      }
      #pragma unroll 2
      for (int ki = 0; ki < 16; ++ki) {
        bf16x8 a0 = cvt8(fa0 + ki * 32);
        bf16x8 a1 = cvt8(fa1 + ki * 32);
        bf16x8 b0 = *(const bf16x8*)(bB0 + ki * 32);
        bf16x8 b1 = *(const bf16x8*)(bB1 + ki * 32);
        acc00 = __builtin_amdgcn_mfma_f32_16x16x32_bf16(a0, b0, acc00, 0, 0, 0);
        acc01 = __builtin_amdgcn_mfma_f32_16x16x32_bf16(a0, b1, acc01, 0, 0, 0);
        acc10 = __builtin_amdgcn_mfma_f32_16x16x32_bf16(a1, b0, acc10, 0, 0, 0);
        acc11 = __builtin_amdgcn_mfma_f32_16x16x32_bf16(a1, b1, acc11, 0, 0, 0);
      }
    }

    // C layout: col = lane&15, row = quad*4 + reg (HW-verified)
    // gparts slices are per-wave disjoint; prior S3 already separates these
    // writes from the previous step's cell-update reads — no barrier needed.
    {
      float* gp = gparts + ksl * (32 * GPS);
      #pragma unroll
      for (int r = 0; r < 4; ++r) {
        gp[(quad * 4 + r) * GPS + m16]           = acc00[r];
        gp[(quad * 4 + r) * GPS + 16 + m16]      = acc01[r];
        gp[(16 + quad * 4 + r) * GPS + m16]      = acc10[r];
        gp[(16 + quad * 4 + r) * GPS + 16 + m16] = acc11[r];
      }
    }
    __syncthreads();   // S2: gparts(t) complete before cell reads

    // ---- cell update: 32 rows x 4 col-pairs (128 threads) ----
    if (tid < 128) {
      int rl = tid >> 2, jp = tid & 3;
      f32x4 ga = {0,0,0,0}, gb = {0,0,0,0};
      #pragma unroll
      for (int s = 0; s < 4; ++s) {
        const float* gp = gparts + s * (32 * GPS) + rl * GPS + jp * 8;
        ga += *(const f32x4*)gp;
        gb += *(const f32x4*)(gp + 4);
      }
      f32x4 ba = *(const f32x4*)(bias_s + jp * 8);
      f32x4 bb = *(const f32x4*)(bias_s + jp * 8 + 4);

      float i0 = sig_(ga[0] + ba[0]);
      float f0 = sig_(ga[1] + ba[1]);
      float g0 = tanh_(ga[2] + ba[2]);
      float o0 = sig_(ga[3] + ba[3]);
      float i1 = sig_(gb[0] + bb[0]);
      float f1 = sig_(gb[1] + bb[1]);
      float g1 = tanh_(gb[2] + bb[2]);
      float o1 = sig_(gb[3] + bb[3]);

      int ci = rl * 8 + jp * 2;
      float c0 = f0 * cst[ci]     + i0 * g0;
      float c1 = f1 * cst[ci + 1] + i1 * g1;
      cst[ci] = c0; cst[ci + 1] = c1;
      float h0v = o0 * tanh_(c0);
      float h1v = o1 * tanh_(c1);

      size_t off = (size_t)(r0 + rl) * HID + j0 + jp * 2;
      if constexpr (MODE == 1) {
        if (t < SEQ - 1) {
          short* hw = (t & 1) ? p.hb0 : p.hb1;
          unsigned u = (unsigned)(unsigned short)f2b(h0v) |
                       ((unsigned)(unsigned short)f2b(h1v) << 16);
          // IF-coherent h store (sc1, compiler-tracked for syncthreads drain)
          __hip_atomic_store((unsigned*)(hw + off), u, __ATOMIC_RELAXED,
                             __HIP_MEMORY_SCOPE_AGENT);
        } else {
          f32x2 hv = {h0v, h1v}; *(f32x2*)(p.out + off) = hv;
          f32x2 cv = {c0, c1};   *(f32x2*)(p.out + 65536 + off) = cv;
        }
      } else {
        float* hw = p.out + ((t & 1) ? 0 : 65536);
        f32x2 hv = {h0v, h1v};
        *(f32x2*)(hw + off) = hv;
        if (t == SEQ - 1) { cfin0 = c0; cfin1 = c1; }
      }
    }

    if constexpr (MODE == 1) {
      // S3: every wave drains its vmcnt (h sc1 stores acked at IF) before the
      // barrier completes; tid0's flag store below is therefore ordered after
      // ALL of this block's h stores at the coherence point.
      __syncthreads();
      if (t < SEQ - 1 && tid == 0)
        __hip_atomic_store(&p.arrive[(size_t)bid * 32], (unsigned)(t + 1),
                           __ATOMIC_RELAXED, __HIP_MEMORY_SCOPE_AGENT);
    } else {
      if (t < SEQ - 1)
        gbar_fence(p.arrive, p.gen, tid, bid, (unsigned)(t + 1));
    }
  }

  if constexpr (MODE == 0) {
    if (tid < 128) {
      int rl = tid >> 2, jp = tid & 3;
      size_t off = (size_t)(r0 + rl) * HID + j0 + jp * 2;
      f32x2 cv = {cfin0, cfin1};
      *(f32x2*)(p.out + 65536 + off) = cv;
    }
  }
}

extern "C" void kernel_launch(void* const* d_in, const int* in_sizes, int n_in,
                              void* d_out, int out_size, void* d_ws, size_t ws_size,
                              hipStream_t stream) {
  Params prm;
  prm.x = (const float*)d_in[0];
  for (int g = 0; g < 4; ++g) {
    prm.Wi[g] = (const float*)d_in[1 + g];
    prm.Wh[g] = (const float*)d_in[5 + g];
    prm.bi[g] = (const float*)d_in[9 + 2 * g];
    prm.bh[g] = (const float*)d_in[10 + 2 * g];
  }
  prm.out    = (float*)d_out;
  prm.arrive = (unsigned*)d_ws;
  prm.gen    = prm.arrive + 8192;          // own 128 B line after slot region
  prm.xbf = nullptr; prm.hb0 = nullptr; prm.hb1 = nullptr;

  const size_t XBF   = 67108864;                      // 64 MiB
  const size_t need1 = 65536 + XBF + 2 * 131072;      // 67,436,544 (known avail.)
  const int mode = (ws_size >= need1) ? 1 : 0;

  if (mode == 1) {
    prm.xbf = (const short*)((char*)d_ws + 65536);
    prm.hb0 = (short*)((char*)d_ws + 65536 + XBF);
    prm.hb1 = prm.hb0 + 65536;
  }

  const int smem_bytes = 131584 + 18432 + 1024 + 128;   // 151168
  hipFuncSetAttribute((const void*)lstm_persistent<1>,
                      hipFuncAttributeMaxDynamicSharedMemorySize, smem_bytes);
  hipFuncSetAttribute((const void*)lstm_persistent<0>,
                      hipFuncAttributeMaxDynamicSharedMemorySize, smem_bytes);

  if (mode == 1) {
    init_ws<<<256, 256, 0, stream>>>((unsigned*)d_ws, (unsigned*)prm.hb0, 32768);
    cvt_x<<<16384, 256, 0, stream>>>(prm.x, (short*)prm.xbf);
    lstm_persistent<1><<<NBLK, NTHR, smem_bytes, stream>>>(prm);
  } else {
    init_ws<<<256, 256, 0, stream>>>((unsigned*)d_ws, (unsigned*)d_out, 65536);
    lstm_persistent<0><<<NBLK, NTHR, smem_bytes, stream>>>(prm);
  }
}